// Round 5
// baseline (242.641 us; speedup 1.0000x reference)
//
#include <hip/hip_runtime.h>

#define BN_EPS 1e-5f
#define ATT_SCALE 0.125f   // 64^-0.5

typedef _Float16 half_t;
typedef _Float16 half8 __attribute__((ext_vector_type(8)));
typedef _Float16 half4 __attribute__((ext_vector_type(4)));
typedef float f32x4 __attribute__((ext_vector_type(4)));

// async global->LDS, 16B per lane; LDS dest = wave-uniform base + lane*16
__device__ __forceinline__ void gll16(const void* g, void* l) {
    __builtin_amdgcn_global_load_lds((const __attribute__((address_space(1))) void*)g,
                                     (__attribute__((address_space(3))) void*)l, 16, 0, 0);
}

// counted vmem wait (N newest ops may remain in flight)
template<int N>
__device__ __forceinline__ void vmwait() {
    asm volatile("s_waitcnt vmcnt(%0)" :: "i"(N) : "memory");
}

// ================= fused prep (BN-fold + weight split) + dw-conv pack =================
__device__ void prep_body(
    int o, int c,
    const float* qg, const float* qb, const float* qm, const float* qv, const float* qpw,
    const float* kg, const float* kbt, const float* km, const float* kvv, const float* kvpw,
    const float* outw,
    half_t* wq, half_t* wkv, half_t* wout, float* bq, float* bkv, float* red)
{
    if (o >= 1536) {   // out_w rows: no BN, just split
        int ro = o - 1536;
        #pragma unroll
        for (int ci = 0; ci < 2; ++ci) {
            int cc = ci * 256 + c;
            float wv = outw[(size_t)ro * 512 + cc];
            half_t hh = (half_t)wv;
            wout[(size_t)ro * 1024 + cc]       = hh;
            wout[(size_t)ro * 1024 + 512 + cc] = (half_t)(wv - (float)hh);
        }
        return;
    }
    const float *g, *b, *m, *v, *w; half_t* we; float* be;
    if (o < 512) {
        g = qg; b = qb; m = qm; v = qv;
        w = qpw + (size_t)o * 256; we = wq + (size_t)o * 512; be = bq + o;
    } else {
        int ro = o - 512;
        g = kg; b = kbt; m = km; v = kvv;
        w = kvpw + (size_t)ro * 256; we = wkv + (size_t)ro * 512; be = bkv + ro;
    }
    float s  = g[c] * rsqrtf(v[c] + BN_EPS);
    float tt = b[c] - m[c] * s;
    float wv = w[c];
    float wsv = wv * s;
    half_t hh = (half_t)wsv;
    we[c]       = hh;
    we[256 + c] = (half_t)(wsv - (float)hh);
    float partial = wv * tt;
    #pragma unroll
    for (int off = 32; off > 0; off >>= 1)
        partial += __shfl_down(partial, off, 64);
    if ((c & 63) == 0) red[c >> 6] = partial;
    __syncthreads();
    if (c == 0) *be = red[0] + red[1] + red[2] + red[3];
}

// dw conv with vectorized padded-LDS window reads.
// sin layout: ch*148 + row*36 + physcol; physcol = logical_col + 2 (logical -2..33).
__device__ void dw_body(
    int rp, int img, float* sin,
    const float* x, const float* y,
    const float* qdw, const float* kvdw,
    half_t* qB, half_t* kvB)
{
    const float* in = (img < 8) ? x + (size_t)img * 256 * 1024
                                : y + (size_t)(img - 8) * 256 * 1024;
    int t = threadIdx.x;
    int ch = t & 63, cg = t >> 6;
    int r0 = 2 * rp - 1;
    // zero pads (physical cols 0,1,34,35) once; staging only writes 2..33
    #pragma unroll
    for (int u = t; u < 1024; u += 256) {
        int c = u >> 4, row = (u >> 2) & 3, pi = u & 3;
        sin[c * 148 + row * 36 + (pi < 2 ? pi : 32 + pi)] = 0.f;
    }
    for (int cc = 0; cc < 4; ++cc) {
        __syncthreads();
        #pragma unroll
        for (int ii = 0; ii < 8; ++ii) {
            int u = ii * 256 + t;            // float4 unit
            int sch = u >> 5, row = (u >> 3) & 3, seg = u & 7;
            int gr = r0 + row;
            float4 v4 = {0.f, 0.f, 0.f, 0.f};
            if (gr >= 0 && gr < 32)
                v4 = *(const float4*)(in + (size_t)(cc * 64 + sch) * 1024 + gr * 32 + seg * 4);
            float* d = &sin[sch * 148 + row * 36 + 2 + seg * 4];  // 8B-aligned
            d[0] = v4.x; d[1] = v4.y; d[2] = v4.z; d[3] = v4.w;
        }
        __syncthreads();
        int gch = cc * 64 + ch;
        float wq9[9], wk9[9];
        #pragma unroll
        for (int i = 0; i < 9; ++i) { wq9[i] = qdw[gch * 9 + i]; wk9[i] = kvdw[gch * 9 + i]; }
        // load 4 rows x 12 floats (physical cg*8 .. cg*8+11 = logical cg*8-2 .. +9)
        float rowv[4][12];
        const float* base = &sin[ch * 148];
        #pragma unroll
        for (int rr = 0; rr < 4; ++rr) {
            *(float4*)&rowv[rr][0] = *(const float4*)(base + rr * 36 + cg * 8);
            *(float4*)&rowv[rr][4] = *(const float4*)(base + rr * 36 + cg * 8 + 4);
            *(float4*)&rowv[rr][8] = *(const float4*)(base + rr * 36 + cg * 8 + 8);
        }
        // q (stride 1): rows 2rp..2rp+1, cols cg*8..+8; tap e = c8+dc+1
        #pragma unroll
        for (int r = 0; r < 2; ++r) {
            #pragma unroll
            for (int c8 = 0; c8 < 8; ++c8) {
                float acc = 0.f;
                #pragma unroll
                for (int dr = 0; dr < 3; ++dr)
                    #pragma unroll
                    for (int dc = 0; dc < 3; ++dc)
                        acc += wq9[dr * 3 + dc] * rowv[r + dr][c8 + dc + 1];
                half_t hh = (half_t)acc;
                size_t p = (size_t)img * 1024 + (2 * rp + r) * 32 + cg * 8 + c8;
                qB[p * 512 + gch]       = hh;
                qB[p * 512 + 256 + gch] = (half_t)(acc - (float)hh);
            }
        }
        // kv (stride 2): row rp, cols cg*4..+4; tap e = 2*c4+dc+1
        #pragma unroll
        for (int c4 = 0; c4 < 4; ++c4) {
            float acc = 0.f;
            #pragma unroll
            for (int dr = 0; dr < 3; ++dr)
                #pragma unroll
                for (int dc = 0; dc < 3; ++dc)
                    acc += wk9[dr * 3 + dc] * rowv[dr][2 * c4 + dc + 1];
            half_t hh = (half_t)acc;
            size_t p = (size_t)img * 256 + rp * 16 + cg * 4 + c4;
            kvB[p * 512 + gch]       = hh;
            kvB[p * 512 + 256 + gch] = (half_t)(acc - (float)hh);
        }
    }
}

__global__ __launch_bounds__(256) void prep_dw_kernel(
    const float* __restrict__ x, const float* __restrict__ y,
    const float* __restrict__ qdw, const float* __restrict__ kvdw,
    const float* __restrict__ qg, const float* __restrict__ qb,
    const float* __restrict__ qm, const float* __restrict__ qv,
    const float* __restrict__ qpw,
    const float* __restrict__ kg, const float* __restrict__ kbt,
    const float* __restrict__ km, const float* __restrict__ kvv,
    const float* __restrict__ kvpw,
    const float* __restrict__ outw,
    half_t* __restrict__ wq, half_t* __restrict__ wkv, half_t* __restrict__ wout,
    float* __restrict__ bq, float* __restrict__ bkv,
    half_t* __restrict__ qB, half_t* __restrict__ kvB)
{
    __shared__ __align__(16) float smem[64 * 148];
    int bx = blockIdx.x;
    if (bx < 256)
        dw_body(bx & 15, bx >> 4, smem, x, y, qdw, kvdw, qB, kvB);
    else
        prep_body(bx - 256, threadIdx.x, qg, qb, qm, qv, qpw,
                  kg, kbt, km, kvv, kvpw, outw, wq, wkv, wout, bq, bkv, smem);
}

// ================= 128x128 split-f16 GEMM worker v2 =================
// 256 threads = 4 waves (2x2), wave tile 64x64 (MT=NT=4): 8 LDS b128 reads feed
// 48 MFMAs per wave-chunk (6 MFMA/read, was 2).  KC=32, NC=KTOT/32 chunks.
// HI planes: gll16 -> LDS, 16KB/buf x2 (dbuf) -> 32KB LDS -> 3+ blocks/CU.
// LO planes: per-wave reg prefetch (T14), ping-ponged (static indexing),
// issued with the stage and covered by the same counted vmcnt(12):
//   per chunk/thread = 4 gll16 + 8 global b128 = 12 vmem ops.
// Ring: issue stage(kc+1)+loadLo(kc+1), vmwait<12> (kc's 12 done), s_barrier,
// compute(kc), s_barrier (WAR).  Loads stay in flight across barriers (T3/T4).
// A [M][2K] hi|lo, B [N][2K] hi|lo; C = sum_k A*B^T (3-term split f16).
// MODE 0: f16 out [(img*8+h)*NPX + n][128]: hi d0, lo 64+d0; (acc+bias[m])*scale
// MODE 1: fragment-order V^T tiles for attn, acc+bias[n]
// MODE 2: fp32 out [img*256 + m][NPX] = acc + bias[m] (direct)
template<int MODE, int KTOT>
__device__ void gemm_w2(char* lds, const half_t* Ab, const half_t* Bb,
                        void* outBuf, const float* bias,
                        int NPX, int img, int m0, int n0, float scale)
{
    constexpr int NC = KTOT / 32;
    int t = threadIdx.x, w = t >> 6, lane = t & 63, quad = lane >> 4, l15 = lane & 15;
    int wm = w & 1, wn = w >> 1;
    f32x4 acc[4][4] = {};

    // stage hi planes of chunk at k-offset kh into buf p (A 8KB @0 | B 8KB @8192)
    auto stage = [&](int kh, int p) {
        char* Ah = lds + p * 16384;
        char* Bh = Ah + 8192;
        #pragma unroll
        for (int ii = 0; ii < 2; ++ii) {
            int u = ii * 256 + t;
            int mt = u >> 6, q = (u >> 4) & 3, r = u & 15;
            gll16(Ab + (size_t)(mt * 16 + r) * (2 * KTOT) + kh + q * 8, Ah + (u & ~63) * 16);
        }
        #pragma unroll
        for (int ii = 0; ii < 2; ++ii) {
            int u = ii * 256 + t;
            int nt = u >> 6, q = (u >> 4) & 3, r = u & 15;
            gll16(Bb + (size_t)(nt * 16 + r) * (2 * KTOT) + kh + q * 8, Bh + (u & ~63) * 16);
        }
    };
    // lo-plane frags direct to regs (per wave); frag = rows (wt*4+i)*16+l15, quad k-seg
    auto loadLo = [&](int kh, half8* alo, half8* blo) {
        #pragma unroll
        for (int mi = 0; mi < 4; ++mi)
            alo[mi] = *(const half8*)(Ab + (size_t)((wm * 4 + mi) * 16 + l15) * (2 * KTOT)
                                      + KTOT + kh + quad * 8);
        #pragma unroll
        for (int ni = 0; ni < 4; ++ni)
            blo[ni] = *(const half8*)(Bb + (size_t)((wn * 4 + ni) * 16 + l15) * (2 * KTOT)
                                      + KTOT + kh + quad * 8);
    };
    auto compute = [&](int p, half8* alo, half8* blo) {
        char* Ah = lds + p * 16384;
        char* Bh = Ah + 8192;
        half8 afh[4];
        #pragma unroll
        for (int mi = 0; mi < 4; ++mi)
            afh[mi] = *(const half8*)(Ah + (wm * 4 + mi) * 1024 + lane * 16);
        __builtin_amdgcn_s_setprio(1);
        #pragma unroll
        for (int ni = 0; ni < 4; ++ni) {
            half8 bh = *(const half8*)(Bh + (wn * 4 + ni) * 1024 + lane * 16);
            #pragma unroll
            for (int mi = 0; mi < 4; ++mi) {
                acc[mi][ni] = __builtin_amdgcn_mfma_f32_16x16x32_f16(afh[mi], bh,      acc[mi][ni], 0, 0, 0);
                acc[mi][ni] = __builtin_amdgcn_mfma_f32_16x16x32_f16(afh[mi], blo[ni], acc[mi][ni], 0, 0, 0);
                acc[mi][ni] = __builtin_amdgcn_mfma_f32_16x16x32_f16(alo[mi], bh,      acc[mi][ni], 0, 0, 0);
            }
        }
        __builtin_amdgcn_s_setprio(0);
    };

    half8 aloA[4], bloA[4], aloB[4], bloB[4];
    stage(0, 0);
    loadLo(0, aloA, bloA);
    #pragma unroll
    for (int kc = 0; kc < NC; ++kc) {
        if (kc + 1 < NC) {
            stage((kc + 1) * 32, (kc + 1) & 1);
            if (kc & 1) loadLo((kc + 1) * 32, aloA, bloA);
            else        loadLo((kc + 1) * 32, aloB, bloB);
            vmwait<12>();                      // chunk kc's 12 vmem ops retired
        } else {
            vmwait<0>();
        }
        __builtin_amdgcn_s_barrier();          // all waves' stage(kc) landed
        __builtin_amdgcn_sched_barrier(0);
        if (kc & 1) compute(kc & 1, aloB, bloB);
        else        compute(kc & 1, aloA, bloA);
        __builtin_amdgcn_s_barrier();          // WAR: buf[kc&1] reads done
        __builtin_amdgcn_sched_barrier(0);
    }

    if (MODE == 2) {
        #pragma unroll
        for (int mi = 0; mi < 4; ++mi) {
            int mrow0 = m0 + wm * 64 + mi * 16 + quad * 4;
            #pragma unroll
            for (int ni = 0; ni < 4; ++ni) {
                int col = n0 + wn * 64 + ni * 16 + l15;
                f32x4 a = acc[mi][ni];
                float* op = (float*)outBuf + (size_t)img * 256 * NPX;
                #pragma unroll
                for (int r = 0; r < 4; ++r)
                    op[(size_t)(mrow0 + r) * NPX + col] = a[r] + bias[mrow0 + r];
            }
        }
    } else {
        // LDS-transposed epilogue: 4 rounds of 32 rows; tbuf [128 n][40 floats]
        __syncthreads();
        float* tbuf = (float*)lds;
        constexpr int TP = 40;
        #pragma unroll
        for (int qtr = 0; qtr < 4; ++qtr) {
            if (wm == (qtr >> 1)) {
                #pragma unroll
                for (int mi2 = 0; mi2 < 2; ++mi2) {
                    int mi = (qtr & 1) * 2 + mi2;
                    #pragma unroll
                    for (int ni = 0; ni < 4; ++ni) {
                        int nloc = wn * 64 + ni * 16 + l15;
                        #pragma unroll
                        for (int r = 0; r < 4; ++r) {
                            float vv = acc[mi][ni][r];
                            int mloc = mi2 * 16 + quad * 4 + r;     // 0..31
                            if (MODE == 0) vv = (vv + bias[m0 + qtr * 32 + mloc]) * scale;
                            else           vv = vv + bias[n0 + nloc];
                            tbuf[nloc * TP + mloc] = vv;
                        }
                    }
                }
            }
            __syncthreads();
            #pragma unroll
            for (int it = 0; it < 2; ++it) {
                int u = it * 256 + t;
                int n = u >> 2, mg = u & 3;
                float vv[8];
                *(float4*)&vv[0] = *(const float4*)&tbuf[n * TP + mg * 8];
                *(float4*)&vv[4] = *(const float4*)&tbuf[n * TP + mg * 8 + 4];
                half8 hv, lv;
                #pragma unroll
                for (int j = 0; j < 8; ++j) {
                    half_t hh = (half_t)vv[j];
                    hv[j] = hh; lv[j] = (half_t)(vv[j] - (float)hh);
                }
                int mglob = m0 + qtr * 32 + mg * 8;
                if (MODE == 0) {
                    int h = mglob >> 6, d0 = mglob & 63;
                    half_t* op = (half_t*)outBuf + ((size_t)(img * 8 + h) * NPX + n0 + n) * 128 + d0;
                    *(half8*)op = hv;
                    *(half8*)(op + 64) = lv;
                } else {
                    // fragment-order V^T write (see attn stageC/PV reads)
                    int nn = n0 + n, h = nn >> 6, d = nn & 63;
                    int j0 = mglob;                       // multiple of 8
                    half_t* op = (half_t*)outBuf + (size_t)(img * 8 + h) * 32768
                               + (j0 >> 5) * 4096 + ((d >> 4) & 3) * 512 + ((j0 >> 4) & 1) * 256
                               + ((j0 >> 2) & 3) * 64 + (d & 15) * 4;
                    half4 a0 = {hv[0], hv[1], hv[2], hv[3]};
                    half4 a1 = {hv[4], hv[5], hv[6], hv[7]};
                    half4 b0 = {lv[0], lv[1], lv[2], lv[3]};
                    half4 b1 = {lv[4], lv[5], lv[6], lv[7]};
                    *(half4*)op               = a0;   // j0..j0+3   (quad q0)
                    *(half4*)(op + 64)        = a1;   // j0+4..j0+7 (quad q0+1)
                    *(half4*)(op + 2048)      = b0;   // lo plane
                    *(half4*)(op + 2048 + 64) = b1;
                }
            }
            __syncthreads();
        }
    }
}

// ---- fused q/k/v projection: 48 128x128 tiles/img, 256 threads, 32KB LDS ----
__global__ __launch_bounds__(256, 2) void qkv_kernel(
    const half_t* __restrict__ wq, const half_t* __restrict__ wkv,
    const half_t* __restrict__ qB, const half_t* __restrict__ kvB,
    const float* __restrict__ bq, const float* __restrict__ bkv,
    half_t* __restrict__ qpr, half_t* __restrict__ kpr, half_t* __restrict__ vpr)
{
    __shared__ __align__(16) char lds[32768];
    int tile = blockIdx.x, img = blockIdx.z;
    if (tile < 32) {        // q': (wq @ dwq + bq)*SCALE  M=512 N=1024 K=256
        int m0 = (tile >> 3) * 128, n0 = (tile & 7) * 128;
        gemm_w2<0, 256>(lds,
            wq + (size_t)m0 * 512,
            qB + (size_t)img * (1024 * 512) + (size_t)n0 * 512,
            qpr, bq, 1024, img, m0, n0, ATT_SCALE);
    } else if (tile < 40) { // k': wkv[0:512] @ dwkv + bkv  M=512 N=256 K=256
        int tt = tile - 32;
        int m0 = (tt >> 1) * 128, n0 = (tt & 1) * 128;
        gemm_w2<0, 256>(lds,
            wkv + (size_t)m0 * 512,
            kvB + (size_t)img * (256 * 512) + (size_t)n0 * 512,
            kpr, bkv, 256, img, m0, n0, 1.0f);
    } else {                // v': (dwkv x wkv[512:]^T) -> fragment-order V^T tiles
        int tt = tile - 40;
        int m0 = (tt >> 2) * 128, n0 = (tt & 3) * 128;
        gemm_w2<1, 256>(lds,
            kvB + (size_t)img * (256 * 512) + (size_t)m0 * 512,
            wkv + (size_t)(512 + n0) * 512,
            vpr, bkv + 512, 512, img, m0, n0, 1.0f);
    }
}

// ---- out-proj: 16 128x128 tiles/img, 256 threads, 256 blocks (1/CU), K=512 ----
__global__ __launch_bounds__(256, 2) void out_kernel(
    const half_t* __restrict__ wout, const half_t* __restrict__ attp,
    const float* __restrict__ outb, float* __restrict__ out)
{
    __shared__ __align__(16) char lds[32768];
    int tile = blockIdx.x, img = blockIdx.z;
    int m0 = (tile >> 3) * 128, n0 = (tile & 7) * 128;
    gemm_w2<2, 512>(lds,
        wout + (size_t)m0 * 1024,
        attp + (size_t)img * (1024 * 1024) + (size_t)n0 * 1024,
        out, outb, 1024, img, m0, n0, 1.0f);
}

// ================= attention v4: counted-vmcnt 16-chunk ring =================
// 512 threads = 8 waves x 16 q-rows -> 128 q/block. Grid: x = h*16+img, y = ic (8).
// Unified ring: chunks 0..7 = K (8KB fragment-major), 8..15 = V (8KB fragment-order,
// straight copy). 4 x 8KB ring buffers; per chunk: vmcnt(2-counted) + raw s_barrier
// (never drain to 0 until tail) -> 2 chunks always in flight across barriers.
// Swapped-operand softmax: S^T in regs; P^T = exp(S^T) fed directly to PV MFMA
// (16x16x16 B-frag layout == C/D layout); row-max at the K->V seam hides under V
// prefetch. Stage = exactly 1 gll16/thread/chunk (the vmcnt counts rely on this).
// LDS 33792B: ring 32KB + epilogue O-rows [128][132 halfs] (reused, after barrier).
__global__ __launch_bounds__(512, 4) void attn_fused(
    const half_t* __restrict__ qb, const half_t* __restrict__ kb,
    const half_t* __restrict__ vb, half_t* __restrict__ att)
{
    __shared__ __align__(16) char lds[33792];
    int ic = blockIdx.y;
    int img = blockIdx.x & 15, h = blockIdx.x >> 4;
    int partner = img ^ 8;
    int t = threadIdx.x, w = t >> 6, lane = t & 63, quad = lane >> 4, l15 = lane & 15;
    const half_t* qp = qb + ((size_t)(img * 8 + h) * 1024 + ic * 128) * 128;
    const half_t* kp = kb + (size_t)(partner * 8 + h) * 256 * 128;
    const half_t* vp = vb + (size_t)(partner * 8 + h) * 32768;   // fragment-order tiles

    // Q frags (B-side): rows i = w*16 + l15; k = kcs*32 + quad*8 (+64 for lo plane)
    half8 qh[2], ql[2];
    #pragma unroll
    for (int kcs = 0; kcs < 2; ++kcs) {
        const half_t* qr = qp + (size_t)(w * 16 + l15) * 128 + kcs * 32 + quad * 8;
        qh[kcs] = *(const half8*)qr;
        ql[kcs] = *(const half8*)(qr + 64);
    }

    // one chunk stage = exactly 1 gll16 per thread
    auto stageC = [&](int c) {
        char* buf = lds + (c & 3) * 8192;
        if (c < 8) {
            int sb = t >> 6, li = t & 63;
            int plane = sb >> 2, ntr = (sb >> 1) & 1, kcs = sb & 1;
            const half_t* g = kp + (size_t)(c * 32 + ntr * 16 + (li & 15)) * 128
                                 + plane * 64 + kcs * 32 + (li >> 4) * 8;
            gll16(g, buf + (t & ~63) * 16);
        } else {
            gll16(vp + (size_t)(c - 8) * 4096 + t * 8, buf + (t & ~63) * 16);
        }
    };

    f32x4 sacc[16] = {};
    f32x4 oacc[4] = {};
    float mx = 0.f, lsum = 0.f;

    stageC(0); stageC(1); stageC(2);

    #pragma unroll
    for (int c = 0; c < 16; ++c) {
        // chunks c+1,c+2 may stay in flight; chunk c must be done after the barrier
        if (c < 14)       vmwait<2>();
        else if (c == 14) vmwait<1>();
        else              vmwait<0>();
        __builtin_amdgcn_s_barrier();
        __builtin_amdgcn_sched_barrier(0);
        if (c + 3 < 16) stageC(c + 3);
        const char* buf = lds + (c & 3) * 8192;
        if (c < 8) {
            __builtin_amdgcn_s_setprio(1);
            #pragma unroll
            for (int kcs = 0; kcs < 2; ++kcs)
                #pragma unroll
                for (int ntr = 0; ntr < 2; ++ntr) {
                    half8 kh = *(const half8*)(buf + (ntr * 2 + kcs) * 1024 + lane * 16);
                    half8 kl = *(const half8*)(buf + 4096 + (ntr * 2 + kcs) * 1024 + lane * 16);
                    f32x4 s = sacc[c * 2 + ntr];
                    s = __builtin_amdgcn_mfma_f32_16x16x32_f16(kh, qh[kcs], s, 0, 0, 0);
                    s = __builtin_amdgcn_mfma_f32_16x16x32_f16(kh, ql[kcs], s, 0, 0, 0);
                    s = __builtin_amdgcn_mfma_f32_16x16x32_f16(kl, qh[kcs], s, 0, 0, 0);
                    sacc[c * 2 + ntr] = s;
                }
            __builtin_amdgcn_s_setprio(0);
        } else {
            if (c == 8) {   // row max over j (runs under V prefetch)
                float m_ = sacc[0][0];
                #pragma unroll
                for (int ti = 0; ti < 16; ++ti)
                    #pragma unroll
                    for (int r = 0; r < 4; ++r) m_ = fmaxf(m_, sacc[ti][r]);
                m_ = fmaxf(m_, __shfl_xor(m_, 16, 64));
                mx = fmaxf(m_, __shfl_xor(m_, 32, 64));
            }
            int jc = c - 8;
            half4 pb[2][2];   // [kk][hi/lo]
            #pragma unroll
            for (int kk = 0; kk < 2; ++kk) {
                f32x4 s = sacc[jc * 2 + kk];
                #pragma unroll
                for (int e = 0; e < 4; ++e) {
                    float pv = __expf(s[e] - mx);
                    lsum += pv;
                    half_t hh = (half_t)pv;
                    pb[kk][0][e] = hh;
                    pb[kk][1][e] = (half_t)(pv - (float)hh);
                }
            }
            __builtin_amdgcn_s_setprio(1);
            #pragma unroll
            for (int mt = 0; mt < 4; ++mt) {
                #pragma unroll
                for (int kk = 0; kk < 2; ++kk) {
                    half4 vh = *(const half4*)(buf + (mt * 2 + kk) * 512 + lane * 8);
                    half4 vl = *(const half4*)(buf + 4096 + (mt * 2 + kk) * 512 + lane * 8);
                    f32x4 o = oacc[mt];
                    o = __builtin_amdgcn_mfma_f32_16x16x16f16(vh, pb[kk][0], o, 0, 0, 0);
                    o = __builtin_amdgcn_mfma_f32_16x16x16f16(vh, pb[kk][1], o, 0, 0, 0);
                    o = __builtin_amdgcn_mfma_f32_16x16x16f16(vl, pb[kk][0], o, 0, 0, 0);
                    oacc[mt] = o;
                }
            }
            __builtin_amdgcn_s_setprio(0);
        }
    }

    // ---- normalize: lsum over quads; inv lane-local (i = l15) ----
    lsum += __shfl_xor(lsum, 16, 64);
    lsum += __shfl_xor(lsum, 32, 64);
    float inv = 1.f / lsum;

    // ---- epilogue: O^T -> [i][hi 64 | lo 64] rows in LDS, coalesced 16B stores ----
    __syncthreads();   // all compute done before overwriting ring
    #pragma unroll
    for (int mt = 0; mt < 4; ++mt)
        #pragma unroll
        for (int r = 0; r < 4; ++r) {
            float vv = oacc[mt][r] * inv;
            half_t hh = (half_t)vv;
            int row = w * 16 + l15;
            int d = mt * 16 + quad * 4 + r;
            *(half_t*)(lds + (row * 132 + d) * 2)      = hh;
            *(half_t*)(lds + (row * 132 + 64 + d) * 2) = (half_t)(vv - (float)hh);
        }
    __syncthreads();
    #pragma unroll
    for (int ii = 0; ii < 4; ++ii) {
        int u = ii * 512 + t;
        int i = u >> 4, seg = (u >> 3) & 1, p8 = u & 7;
        half8 val = *(const half8*)(lds + (i * 132 + seg * 64 + p8 * 8) * 2);
        *(half8*)(att + ((size_t)img * 1024 + ic * 128 + i) * 1024
                  + seg * 512 + h * 64 + p8 * 8) = val;
    }
}

// ================= launch =================
extern "C" void kernel_launch(void* const* d_in, const int* in_sizes, int n_in,
                              void* d_out, int out_size, void* d_ws, size_t ws_size,
                              hipStream_t stream) {
    const float* x    = (const float*)d_in[0];
    const float* y    = (const float*)d_in[1];
    const float* qdw  = (const float*)d_in[2];
    const float* qg   = (const float*)d_in[3];
    const float* qbb  = (const float*)d_in[4];
    const float* qm   = (const float*)d_in[5];
    const float* qv   = (const float*)d_in[6];
    const float* qpw  = (const float*)d_in[7];
    const float* kvdw = (const float*)d_in[8];
    const float* kg   = (const float*)d_in[9];
    const float* kb_  = (const float*)d_in[10];
    const float* km   = (const float*)d_in[11];
    const float* kvv  = (const float*)d_in[12];
    const float* kvpw = (const float*)d_in[13];
    const float* outw = (const float*)d_in[14];
    const float* outb = (const float*)d_in[15];

    char* ws = (char*)d_ws;
    half_t* wq   = (half_t*)(ws);              //  512*512*2  = 524288
    half_t* wkv  = (half_t*)(ws + 524288);     // 1024*512*2  = 1048576
    half_t* wout = (half_t*)(ws + 1572864);    //  256*1024*2 = 524288
    float*  bq   = (float*) (ws + 2097152);
    float*  bkv  = (float*) (ws + 2099200);
    half_t* qpr  = (half_t*)(ws + 2103296);    // 16*8*1024*128*2 = 33554432
    half_t* kpr  = (half_t*)(ws + 35657728);   // 16*8*256*128*2  = 8388608
    half_t* vpr  = (half_t*)(ws + 44046336);   // 16*8*8*8192     = 8388608 (fragment-order)
    half_t* qB   = (half_t*)(ws + 52434944);   // 16*1024*512*2   = 16777216
    half_t* kvB  = (half_t*)(ws + 69212160);   // 16*256*512*2    = 4194304
    half_t* attp = (half_t*)(ws + 52434944);   // aliases qB+kvB (dead by attn time): 33554432
    // total 85,989,376 B

    prep_dw_kernel<<<2048, 256, 0, stream>>>(
        x, y, qdw, kvdw, qg, qbb, qm, qv, qpw, kg, kb_, km, kvv, kvpw, outw,
        wq, wkv, wout, bq, bkv, qB, kvB);

    qkv_kernel<<<dim3(48, 1, 16), 256, 0, stream>>>(
        wq, wkv, qB, kvB, bq, bkv, qpr, kpr, vpr);

    attn_fused<<<dim3(128, 8, 1), 512, 0, stream>>>(qpr, kpr, vpr, attp);

    out_kernel<<<dim3(16, 1, 16), 256, 0, stream>>>(wout, attp, outb, (float*)d_out);
}

// Round 6
// 196.405 us; speedup vs baseline: 1.2354x; 1.2354x over previous
//
#include <hip/hip_runtime.h>

#define BN_EPS 1e-5f
#define ATT_SCALE 0.125f   // 64^-0.5

typedef _Float16 half_t;
typedef _Float16 half8 __attribute__((ext_vector_type(8)));
typedef _Float16 half4 __attribute__((ext_vector_type(4)));
typedef float f32x4 __attribute__((ext_vector_type(4)));

// async global->LDS, 16B per lane; LDS dest = wave-uniform base + lane*16
__device__ __forceinline__ void gll16(const void* g, void* l) {
    __builtin_amdgcn_global_load_lds((const __attribute__((address_space(1))) void*)g,
                                     (__attribute__((address_space(3))) void*)l, 16, 0, 0);
}

// counted vmem wait (N newest ops may remain in flight)
template<int N>
__device__ __forceinline__ void vmwait() {
    asm volatile("s_waitcnt vmcnt(%0)" :: "i"(N) : "memory");
}

// ================= fused prep (BN-fold + weight split) + dw-conv pack =================
__device__ void prep_body(
    int o, int c,
    const float* qg, const float* qb, const float* qm, const float* qv, const float* qpw,
    const float* kg, const float* kbt, const float* km, const float* kvv, const float* kvpw,
    const float* outw,
    half_t* wq, half_t* wkv, half_t* wout, float* bq, float* bkv, float* red)
{
    if (o >= 1536) {   // out_w rows: no BN, just split
        int ro = o - 1536;
        #pragma unroll
        for (int ci = 0; ci < 2; ++ci) {
            int cc = ci * 256 + c;
            float wv = outw[(size_t)ro * 512 + cc];
            half_t hh = (half_t)wv;
            wout[(size_t)ro * 1024 + cc]       = hh;
            wout[(size_t)ro * 1024 + 512 + cc] = (half_t)(wv - (float)hh);
        }
        return;
    }
    const float *g, *b, *m, *v, *w; half_t* we; float* be;
    if (o < 512) {
        g = qg; b = qb; m = qm; v = qv;
        w = qpw + (size_t)o * 256; we = wq + (size_t)o * 512; be = bq + o;
    } else {
        int ro = o - 512;
        g = kg; b = kbt; m = km; v = kvv;
        w = kvpw + (size_t)ro * 256; we = wkv + (size_t)ro * 512; be = bkv + ro;
    }
    float s  = g[c] * rsqrtf(v[c] + BN_EPS);
    float tt = b[c] - m[c] * s;
    float wv = w[c];
    float wsv = wv * s;
    half_t hh = (half_t)wsv;
    we[c]       = hh;
    we[256 + c] = (half_t)(wsv - (float)hh);
    float partial = wv * tt;
    #pragma unroll
    for (int off = 32; off > 0; off >>= 1)
        partial += __shfl_down(partial, off, 64);
    if ((c & 63) == 0) red[c >> 6] = partial;
    __syncthreads();
    if (c == 0) *be = red[0] + red[1] + red[2] + red[3];
}

// dw conv with vectorized padded-LDS window reads.
// sin layout: ch*148 + row*36 + physcol; physcol = logical_col + 2 (logical -2..33).
__device__ void dw_body(
    int rp, int img, float* sin,
    const float* x, const float* y,
    const float* qdw, const float* kvdw,
    half_t* qB, half_t* kvB)
{
    const float* in = (img < 8) ? x + (size_t)img * 256 * 1024
                                : y + (size_t)(img - 8) * 256 * 1024;
    int t = threadIdx.x;
    int ch = t & 63, cg = t >> 6;
    int r0 = 2 * rp - 1;
    // zero pads (physical cols 0,1,34,35) once; staging only writes 2..33
    #pragma unroll
    for (int u = t; u < 1024; u += 256) {
        int c = u >> 4, row = (u >> 2) & 3, pi = u & 3;
        sin[c * 148 + row * 36 + (pi < 2 ? pi : 32 + pi)] = 0.f;
    }
    for (int cc = 0; cc < 4; ++cc) {
        __syncthreads();
        #pragma unroll
        for (int ii = 0; ii < 8; ++ii) {
            int u = ii * 256 + t;            // float4 unit
            int sch = u >> 5, row = (u >> 3) & 3, seg = u & 7;
            int gr = r0 + row;
            float4 v4 = {0.f, 0.f, 0.f, 0.f};
            if (gr >= 0 && gr < 32)
                v4 = *(const float4*)(in + (size_t)(cc * 64 + sch) * 1024 + gr * 32 + seg * 4);
            float* d = &sin[sch * 148 + row * 36 + 2 + seg * 4];  // 8B-aligned
            d[0] = v4.x; d[1] = v4.y; d[2] = v4.z; d[3] = v4.w;
        }
        __syncthreads();
        int gch = cc * 64 + ch;
        float wq9[9], wk9[9];
        #pragma unroll
        for (int i = 0; i < 9; ++i) { wq9[i] = qdw[gch * 9 + i]; wk9[i] = kvdw[gch * 9 + i]; }
        // load 4 rows x 12 floats (physical cg*8 .. cg*8+11 = logical cg*8-2 .. +9)
        float rowv[4][12];
        const float* base = &sin[ch * 148];
        #pragma unroll
        for (int rr = 0; rr < 4; ++rr) {
            *(float4*)&rowv[rr][0] = *(const float4*)(base + rr * 36 + cg * 8);
            *(float4*)&rowv[rr][4] = *(const float4*)(base + rr * 36 + cg * 8 + 4);
            *(float4*)&rowv[rr][8] = *(const float4*)(base + rr * 36 + cg * 8 + 8);
        }
        // q (stride 1): rows 2rp..2rp+1, cols cg*8..+8; tap e = c8+dc+1
        #pragma unroll
        for (int r = 0; r < 2; ++r) {
            #pragma unroll
            for (int c8 = 0; c8 < 8; ++c8) {
                float acc = 0.f;
                #pragma unroll
                for (int dr = 0; dr < 3; ++dr)
                    #pragma unroll
                    for (int dc = 0; dc < 3; ++dc)
                        acc += wq9[dr * 3 + dc] * rowv[r + dr][c8 + dc + 1];
                half_t hh = (half_t)acc;
                size_t p = (size_t)img * 1024 + (2 * rp + r) * 32 + cg * 8 + c8;
                qB[p * 512 + gch]       = hh;
                qB[p * 512 + 256 + gch] = (half_t)(acc - (float)hh);
            }
        }
        // kv (stride 2): row rp, cols cg*4..+4; tap e = 2*c4+dc+1
        #pragma unroll
        for (int c4 = 0; c4 < 4; ++c4) {
            float acc = 0.f;
            #pragma unroll
            for (int dr = 0; dr < 3; ++dr)
                #pragma unroll
                for (int dc = 0; dc < 3; ++dc)
                    acc += wk9[dr * 3 + dc] * rowv[dr][2 * c4 + dc + 1];
            half_t hh = (half_t)acc;
            size_t p = (size_t)img * 256 + rp * 16 + cg * 4 + c4;
            kvB[p * 512 + gch]       = hh;
            kvB[p * 512 + 256 + gch] = (half_t)(acc - (float)hh);
        }
    }
}

__global__ __launch_bounds__(256) void prep_dw_kernel(
    const float* __restrict__ x, const float* __restrict__ y,
    const float* __restrict__ qdw, const float* __restrict__ kvdw,
    const float* __restrict__ qg, const float* __restrict__ qb,
    const float* __restrict__ qm, const float* __restrict__ qv,
    const float* __restrict__ qpw,
    const float* __restrict__ kg, const float* __restrict__ kbt,
    const float* __restrict__ km, const float* __restrict__ kvv,
    const float* __restrict__ kvpw,
    const float* __restrict__ outw,
    half_t* __restrict__ wq, half_t* __restrict__ wkv, half_t* __restrict__ wout,
    float* __restrict__ bq, float* __restrict__ bkv,
    half_t* __restrict__ qB, half_t* __restrict__ kvB)
{
    __shared__ __align__(16) float smem[64 * 148];
    int bx = blockIdx.x;
    if (bx < 256)
        dw_body(bx & 15, bx >> 4, smem, x, y, qdw, kvdw, qB, kvB);
    else
        prep_body(bx - 256, threadIdx.x, qg, qb, qm, qv, qpw,
                  kg, kbt, km, kvv, kvpw, outw, wq, wkv, wout, bq, bkv, smem);
}

// ================= split-f16 MFMA GEMM worker (counted-vmcnt dbuf ring) ==========
// KC=32, NC=KTOT/32 chunks. Per chunk: issue stage(kc+1) FIRST, then
// s_waitcnt vmcnt(GCNT) (waits only stage(kc), issued a full chunk ago),
// raw s_barrier, compute(kc), trailing s_barrier (WAR for stage(kc+2)).
// Loads stay in flight across barriers (T3/T4); setprio around MFMA (T5).
// A [M][2K] hi|lo, B [N][2K] hi|lo; C = sum_k A*B^T. Ab/Bb pre-offset by m0/n0.
// MODE 0 (QK): f16 out [(img*8+h)*NPX + n][128]: hi d0, lo 64+d0; (acc+bias[m])*scale
// MODE 1 (V):  fragment-order V^T tiles for attn (straight-copy staging there)
// MODE 2 (F32): fp32 out [img*256 + m][NPX] = acc + bias[m]  (direct)
template<int MT, int NT, int WGM, int WGN, int NTHR, int MODE, int KTOT>
__device__ __forceinline__ void gemm_worker(
    char* lds, const half_t* Ab, const half_t* Bb,
    void* outBuf, const float* bias,
    int NPX, int img, int m0, int n0, float scale)
{
    constexpr int TM = WGM * MT * 16, TN = WGN * NT * 16;
    constexpr int BUF = (TM + TN) * 128;       // bytes per buffer (A hi/lo + B hi/lo)
    constexpr int NC = KTOT / 32;
    constexpr int GCNT = 8 * (TM + TN) / NTHR; // gll16 per thread per chunk
    int t = threadIdx.x, w = t >> 6, lane = t & 63, quad = lane >> 4, l15 = lane & 15;
    int wm = w % WGM, wn = w / WGM;
    f32x4 acc[MT][NT] = {};

    auto stage = [&](int kh, int p) {   // kh = k offset in halfs
        char* Ah = lds + p * BUF;
        char* Al = Ah + TM * 64;
        char* Bh = Ah + TM * 128;
        char* Bl = Bh + TN * 64;
        #pragma unroll
        for (int ii = 0; ii < TM * 4 / NTHR; ++ii) {
            int u = ii * NTHR + t;
            int mt = u >> 6, q = (u >> 4) & 3, r = u & 15;
            const half_t* g = Ab + (size_t)(mt * 16 + r) * (2 * KTOT) + kh + q * 8;
            gll16(g,        Ah + (u & ~63) * 16);
            gll16(g + KTOT, Al + (u & ~63) * 16);
        }
        #pragma unroll
        for (int ii = 0; ii < TN * 4 / NTHR; ++ii) {
            int u = ii * NTHR + t;
            int nt = u >> 6, q = (u >> 4) & 3, r = u & 15;
            const half_t* g = Bb + (size_t)(nt * 16 + r) * (2 * KTOT) + kh + q * 8;
            gll16(g,        Bh + (u & ~63) * 16);
            gll16(g + KTOT, Bl + (u & ~63) * 16);
        }
    };

    stage(0, 0);
    for (int kc = 0; kc < NC; ++kc) {
        if (kc + 1 < NC) { stage((kc + 1) * 32, (kc + 1) & 1); vmwait<GCNT>(); }
        else             { vmwait<0>(); }
        __builtin_amdgcn_s_barrier();          // all waves' stage(kc) landed
        __builtin_amdgcn_sched_barrier(0);
        char* Ah = lds + (kc & 1) * BUF;
        char* Al = Ah + TM * 64;
        char* Bh = Ah + TM * 128;
        char* Bl = Bh + TN * 64;
        half8 afh[MT], afl[MT];
        #pragma unroll
        for (int mi = 0; mi < MT; ++mi) {
            afh[mi] = *(half8*)(Ah + (wm * MT + mi) * 1024 + lane * 16);
            afl[mi] = *(half8*)(Al + (wm * MT + mi) * 1024 + lane * 16);
        }
        __builtin_amdgcn_s_setprio(1);
        #pragma unroll
        for (int ni = 0; ni < NT; ++ni) {
            half8 bh = *(half8*)(Bh + (wn * NT + ni) * 1024 + lane * 16);
            half8 bl = *(half8*)(Bl + (wn * NT + ni) * 1024 + lane * 16);
            #pragma unroll
            for (int mi = 0; mi < MT; ++mi) {
                acc[mi][ni] = __builtin_amdgcn_mfma_f32_16x16x32_f16(afh[mi], bh, acc[mi][ni], 0, 0, 0);
                acc[mi][ni] = __builtin_amdgcn_mfma_f32_16x16x32_f16(afh[mi], bl, acc[mi][ni], 0, 0, 0);
                acc[mi][ni] = __builtin_amdgcn_mfma_f32_16x16x32_f16(afl[mi], bh, acc[mi][ni], 0, 0, 0);
            }
        }
        __builtin_amdgcn_s_setprio(0);
        __builtin_amdgcn_s_barrier();          // WAR: reads of buf[kc&1] done
        __builtin_amdgcn_sched_barrier(0);
    }

    if (MODE == 2) {
        #pragma unroll
        for (int mi = 0; mi < MT; ++mi) {
            int mrow0 = m0 + wm * MT * 16 + mi * 16 + quad * 4;
            #pragma unroll
            for (int ni = 0; ni < NT; ++ni) {
                int col = n0 + wn * NT * 16 + ni * 16 + l15;
                f32x4 a = acc[mi][ni];
                float* op = (float*)outBuf + (size_t)img * 256 * NPX;
                #pragma unroll
                for (int r = 0; r < 4; ++r)
                    op[(size_t)(mrow0 + r) * NPX + col] = a[r] + bias[mrow0 + r];
            }
        }
    } else {
        // LDS-transposed epilogue: TM in 32-row quarters; tbuf [TN][40 floats]
        __syncthreads();
        float* tbuf = (float*)lds;
        constexpr int TP = 40;
        #pragma unroll
        for (int qtr = 0; qtr < TM / 32; ++qtr) {
            #pragma unroll
            for (int mi = 0; mi < MT; ++mi) {
                int rowblk = wm * MT * 16 + mi * 16;
                if (rowblk >= qtr * 32 && rowblk < qtr * 32 + 32) {
                    int mloc = rowblk - qtr * 32 + quad * 4;
                    #pragma unroll
                    for (int ni = 0; ni < NT; ++ni) {
                        int nloc = wn * NT * 16 + ni * 16 + l15;
                        #pragma unroll
                        for (int r = 0; r < 4; ++r) {
                            float vv = acc[mi][ni][r];
                            if (MODE == 0) vv = (vv + bias[m0 + rowblk + quad * 4 + r]) * scale;
                            else           vv = vv + bias[n0 + nloc];
                            tbuf[nloc * TP + mloc + r] = vv;
                        }
                    }
                }
            }
            __syncthreads();
            #pragma unroll
            for (int it = 0; it < (TN * 4) / NTHR; ++it) {
                int u = it * NTHR + t;
                int n = u >> 2, mg = u & 3;
                float vv[8];
                *(float4*)&vv[0] = *(const float4*)&tbuf[n * TP + mg * 8];
                *(float4*)&vv[4] = *(const float4*)&tbuf[n * TP + mg * 8 + 4];
                half8 hv, lv;
                #pragma unroll
                for (int j = 0; j < 8; ++j) {
                    half_t hh = (half_t)vv[j];
                    hv[j] = hh; lv[j] = (half_t)(vv[j] - (float)hh);
                }
                int mglob = m0 + qtr * 32 + mg * 8;
                if (MODE == 0) {
                    int h = mglob >> 6, d0 = mglob & 63;
                    half_t* op = (half_t*)outBuf + ((size_t)(img * 8 + h) * NPX + n0 + n) * 128 + d0;
                    *(half8*)op = hv;
                    *(half8*)(op + 64) = lv;
                } else {
                    // fragment-order V^T write (see attn stageC/PV reads).
                    int nn = n0 + n, h = nn >> 6, d = nn & 63;
                    int j0 = mglob;                       // multiple of 8
                    half_t* op = (half_t*)outBuf + (size_t)(img * 8 + h) * 32768
                               + (j0 >> 5) * 4096 + ((d >> 4) & 3) * 512 + ((j0 >> 4) & 1) * 256
                               + ((j0 >> 2) & 3) * 64 + (d & 15) * 4;
                    half4 a0 = {hv[0], hv[1], hv[2], hv[3]};
                    half4 a1 = {hv[4], hv[5], hv[6], hv[7]};
                    half4 b0 = {lv[0], lv[1], lv[2], lv[3]};
                    half4 b1 = {lv[4], lv[5], lv[6], lv[7]};
                    *(half4*)op               = a0;   // j0..j0+3   (quad q0)
                    *(half4*)(op + 64)        = a1;   // j0+4..j0+7 (quad q0+1)
                    *(half4*)(op + 2048)      = b0;   // lo plane
                    *(half4*)(op + 2048 + 64) = b1;
                }
            }
            __syncthreads();
        }
    }
}

// ---- fused q/k/v projection: 48 128x128 tiles/img, 512 threads, dbuf 64KB ----
__global__ __launch_bounds__(512, 4) void qkv_kernel(
    const half_t* __restrict__ wq, const half_t* __restrict__ wkv,
    const half_t* __restrict__ qB, const half_t* __restrict__ kvB,
    const float* __restrict__ bq, const float* __restrict__ bkv,
    half_t* __restrict__ qpr, half_t* __restrict__ kpr, half_t* __restrict__ vpr)
{
    __shared__ __align__(16) char lds[65536];
    int tile = blockIdx.x, img = blockIdx.z;
    if (tile < 32) {        // q': (wq @ dwq + bq)*SCALE  M=512 N=1024 K=256
        int m0 = (tile >> 3) * 128, n0 = (tile & 7) * 128;
        gemm_worker<2, 4, 4, 2, 512, 0, 256>(lds,
            wq + (size_t)m0 * 512,
            qB + (size_t)img * (1024 * 512) + (size_t)n0 * 512,
            qpr, bq, 1024, img, m0, n0, ATT_SCALE);
    } else if (tile < 40) { // k': wkv[0:512] @ dwkv + bkv  M=512 N=256 K=256
        int tt = tile - 32;
        int m0 = (tt >> 1) * 128, n0 = (tt & 1) * 128;
        gemm_worker<2, 4, 4, 2, 512, 0, 256>(lds,
            wkv + (size_t)m0 * 512,
            kvB + (size_t)img * (256 * 512) + (size_t)n0 * 512,
            kpr, bkv, 256, img, m0, n0, 1.0f);
    } else {                // v': (dwkv x wkv[512:]^T) -> fragment-order V^T tiles
        int tt = tile - 40;
        int m0 = (tt >> 2) * 128, n0 = (tt & 3) * 128;
        gemm_worker<2, 4, 4, 2, 512, 1, 256>(lds,
            kvB + (size_t)img * (256 * 512) + (size_t)m0 * 512,
            wkv + (size_t)(512 + n0) * 512,
            vpr, bkv + 512, 512, img, m0, n0, 1.0f);
    }
}

// ---- out-proj: 16 128x128 tiles/img, 512 threads, dbuf 64KB, 256 blocks (1/CU) ----
__global__ __launch_bounds__(512, 4) void out_kernel(
    const half_t* __restrict__ wout, const half_t* __restrict__ attp,
    const float* __restrict__ outb, float* __restrict__ out)
{
    __shared__ __align__(16) char lds[65536];
    int tile = blockIdx.x, img = blockIdx.z;
    int m0 = (tile >> 3) * 128, n0 = (tile & 7) * 128;
    gemm_worker<2, 4, 4, 2, 512, 2, 512>(lds,
        wout + (size_t)m0 * 1024,
        attp + (size_t)img * (1024 * 1024) + (size_t)n0 * 1024,
        out, outb, 1024, img, m0, n0, 1.0f);
}

// ================= attention v4: counted-vmcnt 16-chunk ring =================
// 512 threads = 8 waves x 16 q-rows -> 128 q/block. Grid: x = h*16+img, y = ic (8).
// Unified ring: chunks 0..7 = K (8KB fragment-major), 8..15 = V (8KB fragment-order,
// straight copy). 4 x 8KB ring buffers; per chunk: vmcnt(2-counted) + raw s_barrier
// (never drain to 0 until tail) -> 2 chunks always in flight across barriers.
// Swapped-operand softmax: S^T in regs; P^T = exp(S^T) fed directly to PV MFMA
// (16x16x16 B-frag layout == C/D layout); row-max at the K->V seam hides under V
// prefetch. Stage = exactly 1 gll16/thread/chunk (the vmcnt counts rely on this).
// LDS 33792B: ring 32KB + epilogue O-rows [128][132 halfs] (reused, after barrier).
__global__ __launch_bounds__(512, 4) void attn_fused(
    const half_t* __restrict__ qb, const half_t* __restrict__ kb,
    const half_t* __restrict__ vb, half_t* __restrict__ att)
{
    __shared__ __align__(16) char lds[33792];
    int ic = blockIdx.y;
    int img = blockIdx.x & 15, h = blockIdx.x >> 4;
    int partner = img ^ 8;
    int t = threadIdx.x, w = t >> 6, lane = t & 63, quad = lane >> 4, l15 = lane & 15;
    const half_t* qp = qb + ((size_t)(img * 8 + h) * 1024 + ic * 128) * 128;
    const half_t* kp = kb + (size_t)(partner * 8 + h) * 256 * 128;
    const half_t* vp = vb + (size_t)(partner * 8 + h) * 32768;   // fragment-order tiles

    // Q frags (B-side): rows i = w*16 + l15; k = kcs*32 + quad*8 (+64 for lo plane)
    half8 qh[2], ql[2];
    #pragma unroll
    for (int kcs = 0; kcs < 2; ++kcs) {
        const half_t* qr = qp + (size_t)(w * 16 + l15) * 128 + kcs * 32 + quad * 8;
        qh[kcs] = *(const half8*)qr;
        ql[kcs] = *(const half8*)(qr + 64);
    }

    // one chunk stage = exactly 1 gll16 per thread
    auto stageC = [&](int c) {
        char* buf = lds + (c & 3) * 8192;
        if (c < 8) {
            int sb = t >> 6, li = t & 63;
            int plane = sb >> 2, ntr = (sb >> 1) & 1, kcs = sb & 1;
            const half_t* g = kp + (size_t)(c * 32 + ntr * 16 + (li & 15)) * 128
                                 + plane * 64 + kcs * 32 + (li >> 4) * 8;
            gll16(g, buf + (t & ~63) * 16);
        } else {
            gll16(vp + (size_t)(c - 8) * 4096 + t * 8, buf + (t & ~63) * 16);
        }
    };

    f32x4 sacc[16] = {};
    f32x4 oacc[4] = {};
    float mx = 0.f, lsum = 0.f;

    stageC(0); stageC(1); stageC(2);

    #pragma unroll
    for (int c = 0; c < 16; ++c) {
        // chunks c+1,c+2 may stay in flight; chunk c must be done after the barrier
        if (c < 14)       vmwait<2>();
        else if (c == 14) vmwait<1>();
        else              vmwait<0>();
        __builtin_amdgcn_s_barrier();
        __builtin_amdgcn_sched_barrier(0);
        if (c + 3 < 16) stageC(c + 3);
        const char* buf = lds + (c & 3) * 8192;
        if (c < 8) {
            __builtin_amdgcn_s_setprio(1);
            #pragma unroll
            for (int kcs = 0; kcs < 2; ++kcs)
                #pragma unroll
                for (int ntr = 0; ntr < 2; ++ntr) {
                    half8 kh = *(const half8*)(buf + (ntr * 2 + kcs) * 1024 + lane * 16);
                    half8 kl = *(const half8*)(buf + 4096 + (ntr * 2 + kcs) * 1024 + lane * 16);
                    f32x4 s = sacc[c * 2 + ntr];
                    s = __builtin_amdgcn_mfma_f32_16x16x32_f16(kh, qh[kcs], s, 0, 0, 0);
                    s = __builtin_amdgcn_mfma_f32_16x16x32_f16(kh, ql[kcs], s, 0, 0, 0);
                    s = __builtin_amdgcn_mfma_f32_16x16x32_f16(kl, qh[kcs], s, 0, 0, 0);
                    sacc[c * 2 + ntr] = s;
                }
            __builtin_amdgcn_s_setprio(0);
        } else {
            if (c == 8) {   // row max over j (runs under V prefetch)
                float m_ = sacc[0][0];
                #pragma unroll
                for (int ti = 0; ti < 16; ++ti)
                    #pragma unroll
                    for (int r = 0; r < 4; ++r) m_ = fmaxf(m_, sacc[ti][r]);
                m_ = fmaxf(m_, __shfl_xor(m_, 16, 64));
                mx = fmaxf(m_, __shfl_xor(m_, 32, 64));
            }
            int jc = c - 8;
            half4 pb[2][2];   // [kk][hi/lo]
            #pragma unroll
            for (int kk = 0; kk < 2; ++kk) {
                f32x4 s = sacc[jc * 2 + kk];
                #pragma unroll
                for (int e = 0; e < 4; ++e) {
                    float pv = __expf(s[e] - mx);
                    lsum += pv;
                    half_t hh = (half_t)pv;
                    pb[kk][0][e] = hh;
                    pb[kk][1][e] = (half_t)(pv - (float)hh);
                }
            }
            __builtin_amdgcn_s_setprio(1);
            #pragma unroll
            for (int mt = 0; mt < 4; ++mt) {
                #pragma unroll
                for (int kk = 0; kk < 2; ++kk) {
                    half4 vh = *(const half4*)(buf + (mt * 2 + kk) * 512 + lane * 8);
                    half4 vl = *(const half4*)(buf + 4096 + (mt * 2 + kk) * 512 + lane * 8);
                    f32x4 o = oacc[mt];
                    o = __builtin_amdgcn_mfma_f32_16x16x16f16(vh, pb[kk][0], o, 0, 0, 0);
                    o = __builtin_amdgcn_mfma_f32_16x16x16f16(vh, pb[kk][1], o, 0, 0, 0);
                    o = __builtin_amdgcn_mfma_f32_16x16x16f16(vl, pb[kk][0], o, 0, 0, 0);
                    oacc[mt] = o;
                }
            }
            __builtin_amdgcn_s_setprio(0);
        }
    }

    // ---- normalize: lsum over quads; inv lane-local (i = l15) ----
    lsum += __shfl_xor(lsum, 16, 64);
    lsum += __shfl_xor(lsum, 32, 64);
    float inv = 1.f / lsum;

    // ---- epilogue: O^T -> [i][hi 64 | lo 64] rows in LDS, coalesced 16B stores ----
    __syncthreads();   // all compute done before overwriting ring
    #pragma unroll
    for (int mt = 0; mt < 4; ++mt)
        #pragma unroll
        for (int r = 0; r < 4; ++r) {
            float vv = oacc[mt][r] * inv;
            half_t hh = (half_t)vv;
            int row = w * 16 + l15;
            int d = mt * 16 + quad * 4 + r;
            *(half_t*)(lds + (row * 132 + d) * 2)      = hh;
            *(half_t*)(lds + (row * 132 + 64 + d) * 2) = (half_t)(vv - (float)hh);
        }
    __syncthreads();
    #pragma unroll
    for (int ii = 0; ii < 4; ++ii) {
        int u = ii * 512 + t;
        int i = u >> 4, seg = (u >> 3) & 1, p8 = u & 7;
        half8 val = *(const half8*)(lds + (i * 132 + seg * 64 + p8 * 8) * 2);
        *(half8*)(att + ((size_t)img * 1024 + ic * 128 + i) * 1024
                  + seg * 512 + h * 64 + p8 * 8) = val;
    }
}

// ================= launch =================
extern "C" void kernel_launch(void* const* d_in, const int* in_sizes, int n_in,
                              void* d_out, int out_size, void* d_ws, size_t ws_size,
                              hipStream_t stream) {
    const float* x    = (const float*)d_in[0];
    const float* y    = (const float*)d_in[1];
    const float* qdw  = (const float*)d_in[2];
    const float* qg   = (const float*)d_in[3];
    const float* qbb  = (const float*)d_in[4];
    const float* qm   = (const float*)d_in[5];
    const float* qv   = (const float*)d_in[6];
    const float* qpw  = (const float*)d_in[7];
    const float* kvdw = (const float*)d_in[8];
    const float* kg   = (const float*)d_in[9];
    const float* kb_  = (const float*)d_in[10];
    const float* km   = (const float*)d_in[11];
    const float* kvv  = (const float*)d_in[12];
    const float* kvpw = (const float*)d_in[13];
    const float* outw = (const float*)d_in[14];
    const float* outb = (const float*)d_in[15];

    char* ws = (char*)d_ws;
    half_t* wq   = (half_t*)(ws);              //  512*512*2  = 524288
    half_t* wkv  = (half_t*)(ws + 524288);     // 1024*512*2  = 1048576
    half_t* wout = (half_t*)(ws + 1572864);    //  256*1024*2 = 524288
    float*  bq   = (float*) (ws + 2097152);
    float*  bkv  = (float*) (ws + 2099200);
    half_t* qpr  = (half_t*)(ws + 2103296);    // 16*8*1024*128*2 = 33554432
    half_t* kpr  = (half_t*)(ws + 35657728);   // 16*8*256*128*2  = 8388608
    half_t* vpr  = (half_t*)(ws + 44046336);   // 16*8*8*8192     = 8388608 (fragment-order)
    half_t* qB   = (half_t*)(ws + 52434944);   // 16*1024*512*2   = 16777216
    half_t* kvB  = (half_t*)(ws + 69212160);   // 16*256*512*2    = 4194304
    half_t* attp = (half_t*)(ws + 52434944);   // aliases qB+kvB (dead by attn time): 33554432
    // total 85,989,376 B

    prep_dw_kernel<<<2048, 256, 0, stream>>>(
        x, y, qdw, kvdw, qg, qbb, qm, qv, qpw, kg, kb_, km, kvv, kvpw, outw,
        wq, wkv, wout, bq, bkv, qB, kvB);

    qkv_kernel<<<dim3(48, 1, 16), 512, 0, stream>>>(
        wq, wkv, qB, kvB, bq, bkv, qpr, kpr, vpr);

    attn_fused<<<dim3(128, 8, 1), 512, 0, stream>>>(qpr, kpr, vpr, attp);

    out_kernel<<<dim3(16, 1, 16), 512, 0, stream>>>(wout, attp, outb, (float*)d_out);
}